// Round 8
// baseline (292.540 us; speedup 1.0000x reference)
//
#include <hip/hip_runtime.h>

typedef __bf16 bf16;
typedef __bf16 bfx8 __attribute__((ext_vector_type(8)));
typedef __bf16 bfx4 __attribute__((ext_vector_type(4)));
typedef short sx4 __attribute__((ext_vector_type(4)));
typedef float f32x4 __attribute__((ext_vector_type(4)));

#define MFMA_BF16 __builtin_amdgcn_mfma_f32_16x16x32_bf16

static constexpr int Bq = 4, Sq = 2048, Dq = 1024, Hq = 16, HDq = 64;
static constexpr int Mq = Bq * Sq;          // 8192
static constexpr int D3 = 3 * Dq;           // 3072
static constexpr float L2E = 1.4426950408889634f;
static constexpr float QSC = 0.125f * L2E;  // softmax scale folded into Q

typedef const __attribute__((address_space(1))) void* gas1;
typedef __attribute__((address_space(3))) void* las3;

__device__ __forceinline__ void gload_lds16(const bf16* g, bf16* l) {
    __builtin_amdgcn_global_load_lds((gas1)g, (las3)l, 16, 0, 0);
}

__device__ __forceinline__ float fast_exp2(float x) {
    return __builtin_amdgcn_exp2f(x);
}

// K=16 bf16 MFMA: A/B = 4 bf16 (2 VGPRs), k = quad*4 + j  -> P fragment needs
// no layout transform coming out of the K=32 QK^T C-layout.
__device__ __forceinline__ f32x4 mfma16(bfx4 a, bfx4 b, f32x4 c) {
    return __builtin_amdgcn_mfma_f32_16x16x16bf16_1k(
        __builtin_bit_cast(sx4, a), __builtin_bit_cast(sx4, b), c, 0, 0, 0);
}

// ---------------- cast x: fp32 -> bf16 ----------------
__global__ __launch_bounds__(256) void cast_f32_bf16(const float* __restrict__ in,
                                                     bf16* __restrict__ out, int n) {
    int i = (blockIdx.x * 256 + threadIdx.x) * 4;
    if (i + 3 < n) {
        float4 v = *(const float4*)(in + i);
        bfx4 r;
        r[0] = (bf16)v.x; r[1] = (bf16)v.y; r[2] = (bf16)v.z; r[3] = (bf16)v.w;
        *(bfx4*)(out + i) = r;
    }
}

// ---------------- transpose+cast: in fp32 [R][C] -> out bf16 [C][R] ----------------
__global__ __launch_bounds__(256) void transpose_cast(const float* __restrict__ in,
                                                      bf16* __restrict__ out, int R, int C) {
    __shared__ float tile[32][33];
    int tx = threadIdx.x, ty = threadIdx.y;     // 32 x 8
    int c0 = blockIdx.x * 32, r0 = blockIdx.y * 32;
    for (int j = 0; j < 32; j += 8)
        tile[ty + j][tx] = in[(size_t)(r0 + ty + j) * C + c0 + tx];
    __syncthreads();
    for (int j = 0; j < 32; j += 8)
        out[(size_t)(c0 + ty + j) * R + r0 + tx] = (bf16)tile[tx][ty + j];
}

// ---------------- V transpose: qkv V-part [b][s][hd] -> Vt [b][hd][s] (bf16) ----------------
__global__ __launch_bounds__(256) void vtrans(const bf16* __restrict__ qkv,
                                              bf16* __restrict__ Vt) {
    __shared__ bf16 tile[32][33];
    int tx = threadIdx.x, ty = threadIdx.y;     // 32 x 8
    int c0 = blockIdx.x * 32;                   // hd (V column) 0..1023
    int s0 = blockIdx.y * 32;                   // s
    int b = blockIdx.z;
    for (int j = 0; j < 32; j += 8)
        tile[ty + j][tx] = qkv[(size_t)(b * Sq + s0 + ty + j) * D3 + 2 * Dq + c0 + tx];
    __syncthreads();
    for (int j = 0; j < 32; j += 8)
        Vt[((size_t)b * Dq + c0 + ty + j) * Sq + s0 + tx] = tile[tx][ty + j];
}

// ---------------- GEMM: C[M,N] = A[M,K] * Bt[N,K]^T, bf16 in, fp32 acc ----------------
template <bool OUT_F32, bool QSCALE>
__global__ __launch_bounds__(256) void gemm_bt(const bf16* __restrict__ A,
                                               const bf16* __restrict__ Bt,
                                               void* __restrict__ Cout,
                                               int M, int N, int K) {
    __shared__ bf16 As[128 * 64];
    __shared__ bf16 Bs[128 * 64];
    int m0 = blockIdx.y * 128;
    int n0 = blockIdx.x * 128;
    int tid = threadIdx.x;
    int lane = tid & 63, wave = tid >> 6;
    int quad = lane >> 4, l16 = lane & 15;
    int wr = wave >> 1, wc = wave & 1;
    int sw = l16 & 7;

    f32x4 acc[4][4] = {};

    for (int k0 = 0; k0 < K; k0 += 64) {
        __syncthreads();
        #pragma unroll
        for (int i = 0; i < 4; i++) {
            int c = i * 256 + tid;          // LDS dest = wave-uniform + lane*16B
            int row = c >> 3;
            int ch = (c & 7) ^ (row & 7);   // swizzled source chunk
            gload_lds16(A + (size_t)(m0 + row) * K + k0 + ch * 8, As + c * 8);
            gload_lds16(Bt + (size_t)(n0 + row) * K + k0 + ch * 8, Bs + c * 8);
        }
        __syncthreads();
        #pragma unroll
        for (int s = 0; s < 2; s++) {
            bfx8 af[4], bfr[4];
            #pragma unroll
            for (int i = 0; i < 4; i++)
                af[i] = *(const bfx8*)(As + (wr * 64 + i * 16 + l16) * 64 +
                                       ((s * 4 + quad) ^ sw) * 8);
            #pragma unroll
            for (int j = 0; j < 4; j++)
                bfr[j] = *(const bfx8*)(Bs + (wc * 64 + j * 16 + l16) * 64 +
                                        ((s * 4 + quad) ^ sw) * 8);
            #pragma unroll
            for (int i = 0; i < 4; i++)
                #pragma unroll
                for (int j = 0; j < 4; j++)
                    acc[i][j] = MFMA_BF16(af[i], bfr[j], acc[i][j], 0, 0, 0);
        }
    }

    #pragma unroll
    for (int i = 0; i < 4; i++)
        #pragma unroll
        for (int j = 0; j < 4; j++) {
            int col = n0 + wc * 64 + j * 16 + l16;
            float scale = (QSCALE && col < Dq) ? QSC : 1.0f;
            #pragma unroll
            for (int r = 0; r < 4; r++) {
                int row = m0 + wr * 64 + i * 16 + quad * 4 + r;
                if (OUT_F32)
                    ((float*)Cout)[(size_t)row * N + col] = acc[i][j][r];
                else
                    ((bf16*)Cout)[(size_t)row * N + col] = (bf16)(acc[i][j][r] * scale);
            }
        }
}

// ---------------- Flash attention: register-resident P, 32KB LDS ----------------
// 1024 blocks; block = 4 waves; wave owns 32 q rows (128 q/block).
// bid%8 == head%8 -> all 16 q-blocks of one head on one XCD (K/V L2 reuse).
// S^T = K*Q^T (K=32 MFMA) leaves P in exactly the K=16 MFMA A-layout, so
// PV runs 16x16x16 MFMAs straight from registers: no P LDS round-trip.
// Row sums: per-lane f32 adds + cross-quad shfl reduce at epilogue.
__global__ __launch_bounds__(256, 4) void attn_kernel(const bf16* __restrict__ qkv,
                                                      const bf16* __restrict__ Vt,
                                                      bf16* __restrict__ out) {
    __shared__ bf16 Ks[2][64 * 64];
    __shared__ bf16 Vs[2][64 * 64];

    int bid = blockIdx.x;
    int qc = (bid >> 3) & 15;                     // q chunk of 128
    int head = ((bid >> 7) << 3) | (bid & 7);     // 0..63; head%8 == bid%8
    int h = head & 15, b = head >> 4;
    int tid = threadIdx.x;
    int lane = tid & 63, wave = tid >> 6;
    int quad = lane >> 4, l16 = lane & 15;
    int sw = l16 & 7;

    size_t base = (size_t)b * Sq * D3;
    const bf16* Kbase = qkv + base + Dq + h * HDq;
    const bf16* Vbase = Vt + ((size_t)b * Dq + h * HDq) * Sq;
    int q0 = qc * 128 + wave * 32;

    // Q fragments (pre-scaled by QSC in the QKV GEMM)
    bfx8 qf[2][2];
    #pragma unroll
    for (int qt = 0; qt < 2; qt++)
        #pragma unroll
        for (int s = 0; s < 2; s++)
            qf[qt][s] = *(const bfx8*)(qkv + base + (size_t)(q0 + qt * 16 + l16) * D3 +
                                       h * HDq + s * 32 + quad * 8);

    f32x4 oacc[2][4] = {};
    float lsum[2] = {0.f, 0.f};

    // per-thread staging slots (lane-linear LDS dest, swizzled global chunk)
    int c0 = tid, c1 = tid + 256;
    int r0 = c0 >> 3, ch0 = (c0 & 7) ^ (r0 & 7);
    int r1 = c1 >> 3, ch1 = (c1 & 7) ^ (r1 & 7);

    // prologue: chunk 0 -> buffer 0
    gload_lds16(Kbase + (size_t)r0 * D3 + ch0 * 8, Ks[0] + c0 * 8);
    gload_lds16(Vbase + (size_t)r0 * Sq + ch0 * 8, Vs[0] + c0 * 8);
    gload_lds16(Kbase + (size_t)r1 * D3 + ch1 * 8, Ks[0] + c1 * 8);
    gload_lds16(Vbase + (size_t)r1 * Sq + ch1 * 8, Vs[0] + c1 * 8);

    for (int i = 0; i < 32; i++) {
        int cur = i & 1;
        __syncthreads();   // drains prefetch into buf[cur]; fences buf[cur^1] reuse
        if (i + 1 < 32) {  // prefetch next chunk; overlaps the whole compute below
            int k0 = (i + 1) * 64;
            bf16* kd = Ks[cur ^ 1];
            bf16* vd = Vs[cur ^ 1];
            gload_lds16(Kbase + (size_t)(k0 + r0) * D3 + ch0 * 8, kd + c0 * 8);
            gload_lds16(Vbase + (size_t)r0 * Sq + k0 + ch0 * 8, vd + c0 * 8);
            gload_lds16(Kbase + (size_t)(k0 + r1) * D3 + ch1 * 8, kd + c1 * 8);
            gload_lds16(Vbase + (size_t)r1 * Sq + k0 + ch1 * 8, vd + c1 * 8);
        }
        const bf16* K_ = Ks[cur];
        const bf16* V_ = Vs[cur];

        // QK^T: per key-tile t, lane(quad,l16) gets S[q=l16][key=16t+4quad+r]
        // -> exp2 -> pk[qt][t] stays in registers (K=16 A-layout)
        bfx4 pk[2][4];
        #pragma unroll
        for (int t = 0; t < 4; t++) {
            bfx8 kf0 = *(const bfx8*)(K_ + (t * 16 + l16) * 64 + (quad ^ sw) * 8);
            bfx8 kf1 = *(const bfx8*)(K_ + (t * 16 + l16) * 64 + ((4 + quad) ^ sw) * 8);
            #pragma unroll
            for (int qt = 0; qt < 2; qt++) {
                f32x4 s = {};
                s = MFMA_BF16(kf0, qf[qt][0], s, 0, 0, 0);
                s = MFMA_BF16(kf1, qf[qt][1], s, 0, 0, 0);
                bfx4 p;
                float a = 0.f;
                #pragma unroll
                for (int r = 0; r < 4; r++) {
                    float e = fast_exp2(s[r]);
                    p[r] = (bf16)e;
                    a += e;
                }
                pk[qt][t] = p;
                lsum[qt] += a;
            }
        }

        // O += P V via 16x16x16 MFMAs; B-frag = V^T[d=nt*16+l16][key=16t+4quad..+3]
        #pragma unroll
        for (int nt = 0; nt < 4; nt++) {
            #pragma unroll
            for (int t = 0; t < 4; t++) {
                bfx4 vf = *(const bfx4*)(V_ + (nt * 16 + l16) * 64 +
                                         ((2 * t + (quad >> 1)) ^ sw) * 8 + 4 * (quad & 1));
                #pragma unroll
                for (int qt = 0; qt < 2; qt++)
                    oacc[qt][nt] = mfma16(pk[qt][t], vf, oacc[qt][nt]);
            }
        }
    }

    // reduce row sums across quads: after xor 16/32, lane(*,l16) holds l[q=l16]
    float lfull[2];
    #pragma unroll
    for (int qt = 0; qt < 2; qt++) {
        float v = lsum[qt];
        v += __shfl_xor(v, 16);
        v += __shfl_xor(v, 32);
        lfull[qt] = v;
    }

    // epilogue: O rows are q=4*quad+r; fetch l[4quad+r] from lanes 0..15
    #pragma unroll
    for (int qt = 0; qt < 2; qt++)
        #pragma unroll
        for (int r = 0; r < 4; r++) {
            int row = q0 + qt * 16 + quad * 4 + r;
            float inv = 1.0f / __shfl(lfull[qt], quad * 4 + r);
            #pragma unroll
            for (int nt = 0; nt < 4; nt++)
                out[((size_t)b * Sq + row) * Dq + h * HDq + nt * 16 + l16] =
                    (bf16)(oacc[qt][nt][r] * inv);
        }
}

extern "C" void kernel_launch(void* const* d_in, const int* in_sizes, int n_in,
                              void* d_out, int out_size, void* d_ws, size_t ws_size,
                              hipStream_t stream) {
    const float* x     = (const float*)d_in[0];
    const float* w_qkv = (const float*)d_in[1];
    const float* w_out = (const float*)d_in[2];
    float* out = (float*)d_out;

    char* ws = (char*)d_ws;
    bf16* x_bf   = (bf16*)ws;                                   // 16 MB (reused as Vt later)
    bf16* wqkvT  = (bf16*)(ws + 16777216);                      //  6 MB
    bf16* woutT  = (bf16*)(ws + 16777216 + 6291456);            //  2 MB
    bf16* qkv    = (bf16*)(ws + 16777216 + 6291456 + 2097152);  // 48 MB
    bf16* attn   = (bf16*)(ws + 16777216 + 6291456 + 2097152 + 50331648); // 16 MB
    bf16* Vt     = x_bf;   // x_bf dead after gemm1; reuse for V^T

    // 1. casts
    cast_f32_bf16<<<(Mq * Dq) / 4 / 256, 256, 0, stream>>>(x, x_bf, Mq * Dq);
    dim3 tb(32, 8);
    transpose_cast<<<dim3(D3 / 32, Dq / 32), tb, 0, stream>>>(w_qkv, wqkvT, Dq, D3);
    transpose_cast<<<dim3(Dq / 32, Dq / 32), tb, 0, stream>>>(w_out, woutT, Dq, Dq);

    // 2. qkv = x @ w_qkv   [8192 x 3072], Q columns pre-scaled by 0.125*log2(e)
    gemm_bt<false, true><<<dim3(D3 / 128, Mq / 128), 256, 0, stream>>>(x_bf, wqkvT, qkv, Mq, D3, Dq);

    // 3. V transpose (x_bf dead now)
    vtrans<<<dim3(Dq / 32, Sq / 32, Bq), tb, 0, stream>>>(qkv, Vt);

    // 4. attention (1024 blocks, XCD-affine, 4 blocks/CU)
    attn_kernel<<<1024, 256, 0, stream>>>(qkv, Vt, attn);

    // 5. out = attn @ w_out  [8192 x 1024], fp32 out
    gemm_bt<true, false><<<dim3(Dq / 128, Mq / 128), 256, 0, stream>>>(attn, woutT, out, Mq, Dq, Dq);
}